// Round 5
// baseline (237.758 us; speedup 1.0000x reference)
//
#include <hip/hip_runtime.h>

// Problem constants (B,N,F_in,F_out fixed by setup_inputs)
#define NB   4
#define NN   2048
#define FIN  512
#define FOUT 512
#define NHD  8
#define DH   64
#define VC   576   // padded V columns: 512 data (8 heads x 64) + 8 Z cols + 56 zero pad
#define SLOPE 0.2f

typedef __attribute__((ext_vector_type(8)))  short bhalf8;
typedef __attribute__((ext_vector_type(16))) float f32x16;

__device__ __forceinline__ void load_lds16(const void* g, void* l) {
  __builtin_amdgcn_global_load_lds(
      (const __attribute__((address_space(1))) unsigned int*)g,
      (__attribute__((address_space(3))) unsigned int*)l, 16, 0, 0);
}

// RNE float->bf16 pair pack (values finite, no NaN in this pipeline)
__device__ __forceinline__ unsigned int bfpair(float lo, float hi) {
  unsigned int a = __float_as_uint(lo), b = __float_as_uint(hi);
  a = (a + 0x7FFFu + ((a >> 16) & 1u)) >> 16;
  b = (b + 0x7FFFu + ((b >> 16) & 1u)) & 0xFFFF0000u;
  return a | b;
}

// split x,y into bf16 hi (RNE) + bf16 lo (RNE of residual); returns packed pairs
__device__ __forceinline__ void split2(float x, float y,
                                       unsigned int& hp, unsigned int& lp) {
  unsigned int ux = __float_as_uint(x), uy = __float_as_uint(y);
  unsigned int rx = (ux + 0x7FFFu + ((ux >> 16) & 1u)) & 0xFFFF0000u;
  unsigned int ry = (uy + 0x7FFFu + ((uy >> 16) & 1u)) & 0xFFFF0000u;
  float lx = x - __uint_as_float(rx);
  float ly = y - __uint_as_float(ry);
  unsigned int vx = __float_as_uint(lx), vy = __float_as_uint(ly);
  hp = (rx >> 16) | ry;
  lp = ((vx + 0x7FFFu + ((vx >> 16) & 1u)) >> 16)
     | ((vy + 0x7FFFu + ((vy >> 16) & 1u)) & 0xFFFF0000u);
}

// ---------------------------------------------------------------------------
// P1+P2 fused: blocks [0,2048): h -> hHi/hLo split; blocks [2048,2112): Wr
// transpose+split -> wTh/wTl.
// ---------------------------------------------------------------------------
__global__ __launch_bounds__(256) void k_split_prep(
    const float* __restrict__ h,
    unsigned short* __restrict__ hHi, unsigned short* __restrict__ hLo,
    const float* __restrict__ Wr,
    unsigned short* __restrict__ wTh, unsigned short* __restrict__ wTl)
{
  __shared__ float s[64][65];
  const int t = threadIdx.x;
  if (blockIdx.x < 2048) {
    size_t base = ((size_t)blockIdx.x * 256 + t) * 8;
    float4 a = *(const float4*)(h + base);
    float4 b = *(const float4*)(h + base + 4);
    uint4 uh, ul;
    split2(a.x, a.y, uh.x, ul.x);
    split2(a.z, a.w, uh.y, ul.y);
    split2(b.x, b.y, uh.z, ul.z);
    split2(b.z, b.w, uh.w, ul.w);
    *(uint4*)(hHi + base) = uh;
    *(uint4*)(hLo + base) = ul;
    return;
  }
  const int bid2 = blockIdx.x - 2048;
  const int n0 = (bid2 & 7) * 64, k0 = (bid2 >> 3) * 64;
#pragma unroll
  for (int p = 0; p < 4; ++p) {
    int row = p * 16 + (t >> 4);       // k-local
    int col = (t & 15) * 4;            // n-local
    float4 v = *(const float4*)(Wr + (size_t)(k0 + row) * FOUT + n0 + col);
    s[row][col] = v.x; s[row][col+1] = v.y; s[row][col+2] = v.z; s[row][col+3] = v.w;
  }
  __syncthreads();
  const int n = t >> 2;           // 0..63
  const int ks = (t & 3) * 16;    // 0,16,32,48
  uint4 h0, h1, l0, l1;
  split2(s[ks+ 0][n], s[ks+ 1][n], h0.x, l0.x);
  split2(s[ks+ 2][n], s[ks+ 3][n], h0.y, l0.y);
  split2(s[ks+ 4][n], s[ks+ 5][n], h0.z, l0.z);
  split2(s[ks+ 6][n], s[ks+ 7][n], h0.w, l0.w);
  split2(s[ks+ 8][n], s[ks+ 9][n], h1.x, l1.x);
  split2(s[ks+10][n], s[ks+11][n], h1.y, l1.y);
  split2(s[ks+12][n], s[ks+13][n], h1.z, l1.z);
  split2(s[ks+14][n], s[ks+15][n], h1.w, l1.w);
  size_t o = (size_t)(n0 + n) * FIN + k0 + ks;
  *(uint4*)(wTh + o) = h0; *(uint4*)(wTh + o + 8) = h1;
  *(uint4*)(wTl + o) = l0; *(uint4*)(wTl + o + 8) = l1;
}

// ---------------------------------------------------------------------------
// K1: Whr = leaky_relu(h @ Wr) via split-bf16 MFMA (hi*hi + hi*lo + lo*hi).
//     Epilogue also accumulates er[row] = dot(Whr_row, a) via 32-lane shuffle
//     reduction + atomicAdd (each (row-tile, ct) covers all 64 d of one row).
// ---------------------------------------------------------------------------
__global__ __launch_bounds__(256) void k_gemm_whr_mfma(
    const unsigned short* __restrict__ hHi, const unsigned short* __restrict__ hLo,
    const unsigned short* __restrict__ wTh, const unsigned short* __restrict__ wTl,
    float* __restrict__ Whr, const float* __restrict__ av, float* __restrict__ er)
{
  __shared__ unsigned short sAh[128*64], sAl[128*64];
  __shared__ unsigned short sBh[64*64],  sBl[64*64];
  const int tid = threadIdx.x, lane = tid & 63, wv = tid >> 6;
  const int Bid = blockIdx.x;
  const int g8 = Bid & 7, idx = Bid >> 3;     // XCD-grouped: 8 row-groups/XCD
  const int sg = idx >> 3, ct = idx & 7;      // col tiles sweep fastest (share A)
  const int c0 = ct * 64;
  const int row0 = (g8 * 8 + sg) * 128;

  const unsigned short* pAh[4]; const unsigned short* pAl[4];
  unsigned short *dAh[4], *dAl[4];
#pragma unroll
  for (int t = 0; t < 4; ++t) {
    int I  = wv + t * 4;
    int rl = I * 8 + (lane >> 3);
    int gk = (lane & 7) ^ (rl & 7);
    pAh[t] = hHi + (size_t)(row0 + rl) * FIN + gk * 8;
    pAl[t] = hLo + (size_t)(row0 + rl) * FIN + gk * 8;
    dAh[t] = sAh + I * 512;  dAl[t] = sAl + I * 512;
  }
  const unsigned short* pBh[2]; const unsigned short* pBl[2];
  unsigned short *dBh[2], *dBl[2];
#pragma unroll
  for (int t = 0; t < 2; ++t) {
    int I  = wv + t * 4;
    int rl = I * 8 + (lane >> 3);
    int gk = (lane & 7) ^ (rl & 7);
    pBh[t] = wTh + (size_t)(c0 + rl) * FIN + gk * 8;
    pBl[t] = wTl + (size_t)(c0 + rl) * FIN + gk * 8;
    dBh[t] = sBh + I * 512;  dBl[t] = sBl + I * 512;
  }

  const int wi = wv >> 1, wc = wv & 1;
  const int l31 = lane & 31, half = lane >> 5;
  const int aoff0 = (wi*64 +      l31) * 64;
  const int aoff1 = (wi*64 + 32 + l31) * 64;
  const int boff  = (wc*32 +      l31) * 64;
  f32x16 acc0 = {}; f32x16 acc1 = {};

  for (int k0 = 0; k0 < FIN; k0 += 64) {
#pragma unroll
    for (int t = 0; t < 4; ++t) { load_lds16(pAh[t] + k0, dAh[t]);
                                  load_lds16(pAl[t] + k0, dAl[t]); }
#pragma unroll
    for (int t = 0; t < 2; ++t) { load_lds16(pBh[t] + k0, dBh[t]);
                                  load_lds16(pBl[t] + k0, dBl[t]); }
    __syncthreads();
#pragma unroll
    for (int kb = 0; kb < 4; ++kb) {
      int kg = ((kb*2 + half) ^ (lane & 7)) * 8;
      bhalf8 bh  = *(const bhalf8*)&sBh[boff  + kg];
      bhalf8 bl  = *(const bhalf8*)&sBl[boff  + kg];
      bhalf8 a0h = *(const bhalf8*)&sAh[aoff0 + kg];
      bhalf8 a0l = *(const bhalf8*)&sAl[aoff0 + kg];
      bhalf8 a1h = *(const bhalf8*)&sAh[aoff1 + kg];
      bhalf8 a1l = *(const bhalf8*)&sAl[aoff1 + kg];
      acc0 = __builtin_amdgcn_mfma_f32_32x32x16_bf16(a0h, bh, acc0, 0, 0, 0);
      acc1 = __builtin_amdgcn_mfma_f32_32x32x16_bf16(a1h, bh, acc1, 0, 0, 0);
      acc0 = __builtin_amdgcn_mfma_f32_32x32x16_bf16(a0l, bh, acc0, 0, 0, 0);
      acc1 = __builtin_amdgcn_mfma_f32_32x32x16_bf16(a1l, bh, acc1, 0, 0, 0);
      acc0 = __builtin_amdgcn_mfma_f32_32x32x16_bf16(a0h, bl, acc0, 0, 0, 0);
      acc1 = __builtin_amdgcn_mfma_f32_32x32x16_bf16(a1h, bl, acc1, 0, 0, 0);
    }
    __syncthreads();
  }

  // epilogue: leaky_relu + remap + er accumulation (dd = wc*32+l31)
  const float a_d = av[wc*32 + l31];
#pragma unroll
  for (int mi = 0; mi < 2; ++mi) {
    const f32x16 a = mi ? acc1 : acc0;
#pragma unroll
    for (int reg = 0; reg < 16; ++reg) {
      int grow = row0 + wi*64 + mi*32 + ((reg & 3) + 8*(reg >> 2) + 4*half);
      int b  = grow >> 11;
      int n  = grow & 2047;
      int hd = n >> 8;
      int jj = ((n & 255) << 3) | ct;
      int dd = wc*32 + l31;
      float v = a[reg];
      v = v > 0.f ? v : SLOPE * v;
      Whr[(((size_t)(b*NHD + hd)) * NN + jj) * DH + dd] = v;
      float p = v * a_d;
      p += __shfl_xor(p, 16, 32);
      p += __shfl_xor(p,  8, 32);
      p += __shfl_xor(p,  4, 32);
      p += __shfl_xor(p,  2, 32);
      p += __shfl_xor(p,  1, 32);
      if (l31 == 0)
        unsafeAtomicAdd(er + ((size_t)(b*NHD + hd)) * NN + jj, p);
    }
  }
}

// ---------------------------------------------------------------------------
// K3: per (b,h): w[j] = exp(er[j] - max_j er)   (in place), 1 block per (b,h)
// ---------------------------------------------------------------------------
__global__ __launch_bounds__(256) void k_softmax_w(float* __restrict__ er)
{
  __shared__ float wm[4];
  float* p = er + (size_t)blockIdx.x * NN;
  float m = -1e30f;
  for (int j = threadIdx.x; j < NN; j += 256) m = fmaxf(m, p[j]);
#pragma unroll
  for (int off = 32; off; off >>= 1) m = fmaxf(m, __shfl_down(m, off, 64));
  if ((threadIdx.x & 63) == 0) wm[threadIdx.x >> 6] = m;
  __syncthreads();
  float mm = fmaxf(fmaxf(wm[0], wm[1]), fmaxf(wm[2], wm[3]));
  for (int j = threadIdx.x; j < NN; j += 256) p[j] = expf(p[j] - mm);
}

// ---------------------------------------------------------------------------
// K4: Vt[b][c][j] (bf16, j-contiguous for MFMA B-fragments):
//   c<512:       w[b,h,j]*Whr[b,h,j,d]  (h=c>>6, d=c&63)
//   512<=c<520:  w[b,c-512,j]           (denominator columns)
//   else:        0
// ---------------------------------------------------------------------------
__global__ __launch_bounds__(256) void k_build_vt(
    const float* __restrict__ Whr, const float* __restrict__ w,
    unsigned short* __restrict__ Vt)
{
  const int lane = threadIdx.x & 63, wv = threadIdx.x >> 6;
  const int c = blockIdx.y * 4 + wv;     // 0..575
  const int b = blockIdx.z;
  const int j = blockIdx.x * 512 + lane * 8;
  uint4 o = {0u, 0u, 0u, 0u};
  if (c < 512) {
    const int hh = c >> 6, dd = c & 63;
    const size_t r = ((size_t)(b*NHD + hh))*NN + j;
    const float* wp = w + r;
    const float* hp = Whr + r*DH + dd;
    float v[8];
#pragma unroll
    for (int q = 0; q < 8; ++q) v[q] = wp[q] * hp[(size_t)q*DH];
    o.x = bfpair(v[0], v[1]); o.y = bfpair(v[2], v[3]);
    o.z = bfpair(v[4], v[5]); o.w = bfpair(v[6], v[7]);
  } else if (c < 520) {
    const size_t r = ((size_t)(b*NHD + (c - 512)))*NN + j;
    float4 a0 = *(const float4*)(w + r);
    float4 a1 = *(const float4*)(w + r + 4);
    o.x = bfpair(a0.x, a0.y); o.y = bfpair(a0.z, a0.w);
    o.z = bfpair(a1.x, a1.y); o.w = bfpair(a1.z, a1.w);
  }
  *(uint4*)(Vt + ((size_t)(b*VC + c))*NN + j) = o;
}

// ---------------------------------------------------------------------------
// K5: C[8192][576] += adj(0/1 bf16) @ Vt^T per batch, MFMA 32x32x16 bf16.
//     Split-K=2 (kh halves of 1024), partials combined via f32 atomicAdd
//     into zero-init'd C.  Grid 1152 -> 4.5 blocks/CU.
// ---------------------------------------------------------------------------
__global__ __launch_bounds__(256) void k_attn_mfma(
    const int* __restrict__ adj, const unsigned short* __restrict__ Vt,
    float* __restrict__ C)
{
  __shared__ unsigned short sA[128][72];   // [i][k], +8 pad
  __shared__ unsigned short sB[64][64];    // [c][k], unpadded (lds-DMA target)
  const int tid = threadIdx.x;
  const int lane = tid & 63, wv = tid >> 6;
  const int Bid = blockIdx.x;
  const int g8 = Bid & 7;                      // XCD
  const int kh = (Bid >> 3) & 1;               // K half
  const int idx = Bid >> 4;
  const int ct = idx >> 3, sg = idx & 7;       // ct: 0..8, sg: 0..7
  const int c0 = ct * 64;
  const int row0 = (g8 * 8 + sg) * 128;        // flat row in [0,8192)
  const int b = row0 >> 11;

  const unsigned short* pB[2];
  unsigned short* dB[2];
#pragma unroll
  for (int t = 0; t < 2; ++t) {
    int I  = wv + t*4;
    int rl = I*8 + (lane >> 3);
    int gk = (lane & 7) ^ (rl & 7);
    pB[t] = Vt + ((size_t)(b*VC + c0 + rl))*NN + gk*8;
    dB[t] = &sB[0][0] + I*512;
  }
  const int* adjp = adj + (size_t)b*NN*NN + (size_t)(row0 & 2047)*NN
                    + (tid >> 3)*NN + (tid & 7)*8;
  unsigned short* sAp = &sA[tid >> 3][(tid & 7)*8];

  const int wi = wv >> 1, wc = wv & 1;
  const int l31 = lane & 31, half = lane >> 5;
  f32x16 acc0 = {}; f32x16 acc1 = {};
  const unsigned short* aRd0 = &sA[wi*64 +      l31][half*8];
  const unsigned short* aRd1 = &sA[wi*64 + 32 + l31][half*8];
  const int nloc = wc*32 + l31;

  const int kbeg = kh * 1024, kend = kbeg + 1024;
  for (int k0 = kbeg; k0 < kend; k0 += 64) {
    load_lds16(pB[0] + k0, dB[0]);
    load_lds16(pB[1] + k0, dB[1]);
#pragma unroll
    for (int rr = 0; rr < 4; ++rr) {
      const int* p = adjp + rr*32*NN + k0;
      int4 q0 = *(const int4*)p;
      int4 q1 = *(const int4*)(p + 4);
      uint4 u;
      u.x = (unsigned)(q0.x | (q0.y << 16)) * 0x3F80u;
      u.y = (unsigned)(q0.z | (q0.w << 16)) * 0x3F80u;
      u.z = (unsigned)(q1.x | (q1.y << 16)) * 0x3F80u;
      u.w = (unsigned)(q1.z | (q1.w << 16)) * 0x3F80u;
      *(uint4*)(sAp + rr*32*72) = u;
    }
    __syncthreads();
#pragma unroll
    for (int kb = 0; kb < 4; ++kb) {
      int kg = (kb*2 + half) ^ (lane & 7);
      bhalf8 bf = *(const bhalf8*)&sB[nloc][kg*8];
      bhalf8 a0 = *(const bhalf8*)(aRd0 + kb*16);
      bhalf8 a1 = *(const bhalf8*)(aRd1 + kb*16);
      acc0 = __builtin_amdgcn_mfma_f32_32x32x16_bf16(a0, bf, acc0, 0, 0, 0);
      acc1 = __builtin_amdgcn_mfma_f32_32x32x16_bf16(a1, bf, acc1, 0, 0, 0);
    }
    __syncthreads();
  }
  float* Cp = C + ((size_t)(row0 + wi*64))*VC + c0 + wc*32 + l31;
#pragma unroll
  for (int mi = 0; mi < 2; ++mi) {
    const f32x16 a = mi ? acc1 : acc0;
#pragma unroll
    for (int reg = 0; reg < 16; ++reg) {
      int irow = (reg & 3) + 8*(reg >> 2) + 4*half + mi*32;
      unsafeAtomicAdd(Cp + (size_t)irow * VC, a[reg]);
    }
  }
}

// ---------------------------------------------------------------------------
// K6: out[b][n][f] = elu( C[b][i][h*64+d] / C[b][i][512+h] )
//     n = h*256 + (i>>3), f = (i&7)*64 + d
// ---------------------------------------------------------------------------
__global__ __launch_bounds__(256) void k_epilogue(
    const float* __restrict__ C, float* __restrict__ out)
{
  int idx = blockIdx.x * 256 + threadIdx.x;  // ((b*NN+i)*8+h)*64+d
  int d  = idx & 63;
  int t  = idx >> 6;
  int hh = t & 7;
  int bi = t >> 3;           // b*NN + i
  int i  = bi & 2047, b = bi >> 11;
  float num = C[(size_t)bi * VC + (hh << 6) + d];
  float den = C[(size_t)bi * VC + 512 + hh];
  float v = num / den;
  v = v > 0.f ? v : expm1f(v);
  int n = (hh << 8) | (i >> 3);
  int f = ((i & 7) << 6) | d;
  out[((size_t)b * NN + n) * FOUT + f] = v;
}

// ---------------------------------------------------------------------------
extern "C" void kernel_launch(void* const* d_in, const int* in_sizes, int n_in,
                              void* d_out, int out_size, void* d_ws, size_t ws_size,
                              hipStream_t stream)
{
  const float* hin = (const float*)d_in[0];   // h   f32 [4,2048,512]
  const int*   adj = (const int*)d_in[1];     // adj int32 [4,2048,2048]
  // d_in[2] = W_l : mathematically dead (softmax(el[i]+er[j]) == softmax(er[j]))
  const float* Wr  = (const float*)d_in[3];   // W_r f32 [512,512]
  const float* av  = (const float*)d_in[4];   // a   f32 [64,1]
  float* out = (float*)d_out;

  // Workspace overlays (peak 36.7 MB):
  //   [0, 8.39M)      hHi        -> dead after gemm; overlaid by Vt
  //   [8.39M, 16.78M) hLo        -> dead after gemm; overlaid by Vt tail
  //   [16.78M,17.30M) WrT_hi     -> dead after gemm
  //   [17.30M,17.83M) WrT_lo     -> dead after gemm
  //   [17.83M,34.60M) Whr (f32)  -> dead after build_vt; overlaid by C
  //   [34.60M,34.86M) wexp       -> er (atomic) then w in place
  //   [0, 9.44M)      Vt (bf16)  (after gemm)
  //   [17.83M,36.70M) C (f32)    (after build_vt; zero-init for split-K atomics)
  char* ws = (char*)d_ws;
  unsigned short* hHi = (unsigned short*)(ws);
  unsigned short* hLo = (unsigned short*)(ws + 8388608);
  unsigned short* wTh = (unsigned short*)(ws + 16777216);
  unsigned short* wTl = (unsigned short*)(ws + 17301504);
  float* Whr  = (float*)(ws + 17825792);
  float* wexp = (float*)(ws + 34603008);
  unsigned short* Vt = (unsigned short*)(ws);
  float* C    = (float*)(ws + 17825792);

  hipMemsetAsync(wexp, 0, (size_t)NB*NHD*NN*4, stream);        // er zero-init
  k_split_prep   <<<dim3(2112),           256, 0, stream>>>(hin, hHi, hLo, Wr, wTh, wTl);
  k_gemm_whr_mfma<<<dim3(512),            256, 0, stream>>>(hHi, hLo, wTh, wTl, Whr, av, wexp);
  k_softmax_w    <<<dim3(NB*NHD),         256, 0, stream>>>(wexp);
  k_build_vt     <<<dim3(NN/512, VC/4, NB), 256, 0, stream>>>(Whr, wexp, Vt);
  hipMemsetAsync(C, 0, (size_t)NB*NN*VC*4, stream);            // C zero-init
  k_attn_mfma    <<<dim3(1152),           256, 0, stream>>>(adj, Vt, C);
  k_epilogue     <<<dim3(NB*NN*FOUT/256), 256, 0, stream>>>(C, out);
}

// Round 6
// 198.825 us; speedup vs baseline: 1.1958x; 1.1958x over previous
//
#include <hip/hip_runtime.h>

// Problem constants (B,N,F_in,F_out fixed by setup_inputs)
#define NB   4
#define NN   2048
#define FIN  512
#define FOUT 512
#define NHD  8
#define DH   64
#define VTR  520   // Vt rows per batch: 512 data (8 heads x 64 d) + 8 denominator
#define SLOPE 0.2f

typedef __attribute__((ext_vector_type(8)))  short bhalf8;
typedef __attribute__((ext_vector_type(16))) float f32x16;

__device__ __forceinline__ void load_lds16(const void* g, void* l) {
  __builtin_amdgcn_global_load_lds(
      (const __attribute__((address_space(1))) unsigned int*)g,
      (__attribute__((address_space(3))) unsigned int*)l, 16, 0, 0);
}

// RNE float->bf16 (finite values only in this pipeline)
__device__ __forceinline__ unsigned short bfrne(float x) {
  unsigned int u = __float_as_uint(x);
  return (unsigned short)((u + 0x7FFFu + ((u >> 16) & 1u)) >> 16);
}

// split x,y into bf16 hi (RNE) + bf16 lo (RNE of residual); returns packed pairs
__device__ __forceinline__ void split2(float x, float y,
                                       unsigned int& hp, unsigned int& lp) {
  unsigned int ux = __float_as_uint(x), uy = __float_as_uint(y);
  unsigned int rx = (ux + 0x7FFFu + ((ux >> 16) & 1u)) & 0xFFFF0000u;
  unsigned int ry = (uy + 0x7FFFu + ((uy >> 16) & 1u)) & 0xFFFF0000u;
  float lx = x - __uint_as_float(rx);
  float ly = y - __uint_as_float(ry);
  unsigned int vx = __float_as_uint(lx), vy = __float_as_uint(ly);
  hp = (rx >> 16) | ry;
  lp = ((vx + 0x7FFFu + ((vx >> 16) & 1u)) >> 16)
     | ((vy + 0x7FFFu + ((vy >> 16) & 1u)) & 0xFFFF0000u);
}

// ---------------------------------------------------------------------------
// P: blocks [0,2048): h -> hHi/hLo split; [2048,2112): Wr transpose+split.
// ---------------------------------------------------------------------------
__global__ __launch_bounds__(256) void k_split_prep(
    const float* __restrict__ h,
    unsigned short* __restrict__ hHi, unsigned short* __restrict__ hLo,
    const float* __restrict__ Wr,
    unsigned short* __restrict__ wTh, unsigned short* __restrict__ wTl)
{
  __shared__ float s[64][65];
  const int t = threadIdx.x;
  if (blockIdx.x < 2048) {
    size_t base = ((size_t)blockIdx.x * 256 + t) * 8;
    float4 a = *(const float4*)(h + base);
    float4 b = *(const float4*)(h + base + 4);
    uint4 uh, ul;
    split2(a.x, a.y, uh.x, ul.x);
    split2(a.z, a.w, uh.y, ul.y);
    split2(b.x, b.y, uh.z, ul.z);
    split2(b.z, b.w, uh.w, ul.w);
    *(uint4*)(hHi + base) = uh;
    *(uint4*)(hLo + base) = ul;
    return;
  }
  const int bid2 = blockIdx.x - 2048;
  const int n0 = (bid2 & 7) * 64, k0 = (bid2 >> 3) * 64;
#pragma unroll
  for (int p = 0; p < 4; ++p) {
    int row = p * 16 + (t >> 4);       // k-local
    int col = (t & 15) * 4;            // n-local
    float4 v = *(const float4*)(Wr + (size_t)(k0 + row) * FOUT + n0 + col);
    s[row][col] = v.x; s[row][col+1] = v.y; s[row][col+2] = v.z; s[row][col+3] = v.w;
  }
  __syncthreads();
  const int n = t >> 2;           // 0..63
  const int ks = (t & 3) * 16;    // 0,16,32,48
  uint4 h0, h1, l0, l1;
  split2(s[ks+ 0][n], s[ks+ 1][n], h0.x, l0.x);
  split2(s[ks+ 2][n], s[ks+ 3][n], h0.y, l0.y);
  split2(s[ks+ 4][n], s[ks+ 5][n], h0.z, l0.z);
  split2(s[ks+ 6][n], s[ks+ 7][n], h0.w, l0.w);
  split2(s[ks+ 8][n], s[ks+ 9][n], h1.x, l1.x);
  split2(s[ks+10][n], s[ks+11][n], h1.y, l1.y);
  split2(s[ks+12][n], s[ks+13][n], h1.z, l1.z);
  split2(s[ks+14][n], s[ks+15][n], h1.w, l1.w);
  size_t o = (size_t)(n0 + n) * FIN + k0 + ks;
  *(uint4*)(wTh + o) = h0; *(uint4*)(wTh + o + 8) = h1;
  *(uint4*)(wTl + o) = l0; *(uint4*)(wTl + o + 8) = l1;
}

// ---------------------------------------------------------------------------
// K1: Whr = leaky_relu(h @ Wr) split-bf16 MFMA. Epilogue computes er[row]
//     (dot with a) via 32-lane shuffle + LDS combine of the 2 col-waves ->
//     plain store (no atomics, no memset). Each (row,ct) block covers all
//     64 d's of er-row jj = ((n&255)<<3)|ct.
// ---------------------------------------------------------------------------
__global__ __launch_bounds__(256) void k_gemm_whr_mfma(
    const unsigned short* __restrict__ hHi, const unsigned short* __restrict__ hLo,
    const unsigned short* __restrict__ wTh, const unsigned short* __restrict__ wTl,
    float* __restrict__ Whr, const float* __restrict__ av, float* __restrict__ er)
{
  __shared__ unsigned short sAh[128*64], sAl[128*64];
  __shared__ unsigned short sBh[64*64],  sBl[64*64];
  __shared__ float erT[128][2];
  const int tid = threadIdx.x, lane = tid & 63, wv = tid >> 6;
  const int Bid = blockIdx.x;
  const int g8 = Bid & 7, idx = Bid >> 3;     // XCD-grouped
  const int sg = idx >> 3, ct = idx & 7;      // col tiles sweep fastest
  const int c0 = ct * 64;
  const int row0 = (g8 * 8 + sg) * 128;

  const unsigned short* pAh[4]; const unsigned short* pAl[4];
  unsigned short *dAh[4], *dAl[4];
#pragma unroll
  for (int t = 0; t < 4; ++t) {
    int I  = wv + t * 4;
    int rl = I * 8 + (lane >> 3);
    int gk = (lane & 7) ^ (rl & 7);
    pAh[t] = hHi + (size_t)(row0 + rl) * FIN + gk * 8;
    pAl[t] = hLo + (size_t)(row0 + rl) * FIN + gk * 8;
    dAh[t] = sAh + I * 512;  dAl[t] = sAl + I * 512;
  }
  const unsigned short* pBh[2]; const unsigned short* pBl[2];
  unsigned short *dBh[2], *dBl[2];
#pragma unroll
  for (int t = 0; t < 2; ++t) {
    int I  = wv + t * 4;
    int rl = I * 8 + (lane >> 3);
    int gk = (lane & 7) ^ (rl & 7);
    pBh[t] = wTh + (size_t)(c0 + rl) * FIN + gk * 8;
    pBl[t] = wTl + (size_t)(c0 + rl) * FIN + gk * 8;
    dBh[t] = sBh + I * 512;  dBl[t] = sBl + I * 512;
  }

  const int wi = wv >> 1, wc = wv & 1;
  const int l31 = lane & 31, half = lane >> 5;
  const int aoff0 = (wi*64 +      l31) * 64;
  const int aoff1 = (wi*64 + 32 + l31) * 64;
  const int boff  = (wc*32 +      l31) * 64;
  f32x16 acc0 = {}; f32x16 acc1 = {};

  for (int k0 = 0; k0 < FIN; k0 += 64) {
#pragma unroll
    for (int t = 0; t < 4; ++t) { load_lds16(pAh[t] + k0, dAh[t]);
                                  load_lds16(pAl[t] + k0, dAl[t]); }
#pragma unroll
    for (int t = 0; t < 2; ++t) { load_lds16(pBh[t] + k0, dBh[t]);
                                  load_lds16(pBl[t] + k0, dBl[t]); }
    __syncthreads();
#pragma unroll
    for (int kb = 0; kb < 4; ++kb) {
      int kg = ((kb*2 + half) ^ (lane & 7)) * 8;
      bhalf8 bh  = *(const bhalf8*)&sBh[boff  + kg];
      bhalf8 bl  = *(const bhalf8*)&sBl[boff  + kg];
      bhalf8 a0h = *(const bhalf8*)&sAh[aoff0 + kg];
      bhalf8 a0l = *(const bhalf8*)&sAl[aoff0 + kg];
      bhalf8 a1h = *(const bhalf8*)&sAh[aoff1 + kg];
      bhalf8 a1l = *(const bhalf8*)&sAl[aoff1 + kg];
      acc0 = __builtin_amdgcn_mfma_f32_32x32x16_bf16(a0h, bh, acc0, 0, 0, 0);
      acc1 = __builtin_amdgcn_mfma_f32_32x32x16_bf16(a1h, bh, acc1, 0, 0, 0);
      acc0 = __builtin_amdgcn_mfma_f32_32x32x16_bf16(a0l, bh, acc0, 0, 0, 0);
      acc1 = __builtin_amdgcn_mfma_f32_32x32x16_bf16(a1l, bh, acc1, 0, 0, 0);
      acc0 = __builtin_amdgcn_mfma_f32_32x32x16_bf16(a0h, bl, acc0, 0, 0, 0);
      acc1 = __builtin_amdgcn_mfma_f32_32x32x16_bf16(a1h, bl, acc1, 0, 0, 0);
    }
    __syncthreads();
  }

  // epilogue: leaky_relu + remap store + er partial (dd = wc*32+l31)
  const float a_d = av[wc*32 + l31];
#pragma unroll
  for (int mi = 0; mi < 2; ++mi) {
    const f32x16 a = mi ? acc1 : acc0;
#pragma unroll
    for (int reg = 0; reg < 16; ++reg) {
      int rmap = (reg & 3) + 8*(reg >> 2) + 4*half;
      int rowloc = wi*64 + mi*32 + rmap;
      int grow = row0 + rowloc;
      int b  = grow >> 11;
      int n  = grow & 2047;
      int hd = n >> 8;
      int jj = ((n & 255) << 3) | ct;
      float v = a[reg];
      v = v > 0.f ? v : SLOPE * v;
      Whr[(((size_t)(b*NHD + hd)) * NN + jj) * DH + (wc*32 + l31)] = v;
      float p = v * a_d;
      p += __shfl_xor(p, 16, 32);
      p += __shfl_xor(p,  8, 32);
      p += __shfl_xor(p,  4, 32);
      p += __shfl_xor(p,  2, 32);
      p += __shfl_xor(p,  1, 32);
      if (l31 == 0) erT[rowloc][wc] = p;
    }
  }
  __syncthreads();
  if (tid < 128) {
    int grow = row0 + tid;
    int b  = grow >> 11;
    int n  = grow & 2047;
    int hd = n >> 8;
    int jj = ((n & 255) << 3) | ct;
    er[((size_t)(b*NHD + hd)) * NN + jj] = erT[tid][0] + erT[tid][1];
  }
}

// ---------------------------------------------------------------------------
// K2: fused softmax + Vt build. Grid (jc=8, h=8, b=4); block owns (b,h) head,
//     j-chunk of 256. Computes max over full er row (redundant, cheap),
//     w = exp(er-max); writes den row (Vt row 512+h) and the 64 d-rows of
//     head h (Vt rows h*64..h*64+64) via an LDS-transposed bf16 tile.
// ---------------------------------------------------------------------------
__global__ __launch_bounds__(256) void k_softvt(
    const float* __restrict__ Whr, const float* __restrict__ er,
    unsigned short* __restrict__ Vt)
{
  __shared__ float wm[4];
  __shared__ float wbuf[256];
  __shared__ unsigned short tile[64][264];   // [d][j-local], padded
  const int tid = threadIdx.x;
  const int jc = blockIdx.x, hh = blockIdx.y, b = blockIdx.z;
  const float* ep = er + ((size_t)(b*NHD + hh)) * NN;
  float m = -1e30f;
  for (int j = tid; j < NN; j += 256) m = fmaxf(m, ep[j]);
#pragma unroll
  for (int off = 32; off; off >>= 1) m = fmaxf(m, __shfl_down(m, off, 64));
  if ((tid & 63) == 0) wm[tid >> 6] = m;
  __syncthreads();
  const float mm = fmaxf(fmaxf(wm[0], wm[1]), fmaxf(wm[2], wm[3]));
  const int j0 = jc * 256;
  float w = expf(ep[j0 + tid] - mm);
  wbuf[tid] = w;
  Vt[((size_t)(b*VTR + 512 + hh)) * NN + j0 + tid] = bfrne(w);
  __syncthreads();
  const size_t wbase = ((size_t)(b*NHD + hh)) * NN;
#pragma unroll
  for (int p = 0; p < 16; ++p) {
    int jr = p*16 + (tid >> 4);
    int dc = (tid & 15) * 4;
    float4 v = *(const float4*)(Whr + (wbase + j0 + jr) * DH + dc);
    float wj = wbuf[jr];
    tile[dc+0][jr] = bfrne(v.x * wj);
    tile[dc+1][jr] = bfrne(v.y * wj);
    tile[dc+2][jr] = bfrne(v.z * wj);
    tile[dc+3][jr] = bfrne(v.w * wj);
  }
  __syncthreads();
#pragma unroll
  for (int q = 0; q < 8; ++q) {
    int idx = q*256 + tid;
    int d = idx >> 5, seg = idx & 31;
    uint4 t16 = *(const uint4*)&tile[d][seg*8];
    *(uint4*)(Vt + ((size_t)(b*VTR + hh*64 + d)) * NN + j0 + seg*8) = t16;
  }
}

// ---------------------------------------------------------------------------
// K3: fused attention matmul + epilogue. Per block (ct 0..7, row-stripe):
//     num tile [128 x 64d] via acc0/acc1; den via acc2 against den rows
//     (sB rows 64..71; rows 72..95 zeroed so the 32-wide MFMA is safe).
//     Then v = num/den, elu, raw-reshape remap, direct store to out.
// ---------------------------------------------------------------------------
__global__ __launch_bounds__(256) void k_attn_out(
    const int* __restrict__ adj, const unsigned short* __restrict__ Vt,
    float* __restrict__ out)
{
  __shared__ unsigned short sA[128][72];   // [i][k], +8 pad (ds_write staging)
  __shared__ unsigned short sB[96][64];    // [c][k]: 0..63 data, 64..71 den, 72..95 zero
  __shared__ float denL[128];
  const int tid = threadIdx.x;
  const int lane = tid & 63, wv = tid >> 6;
  const int Bid = blockIdx.x;
  const int g8 = Bid & 7, rest = Bid >> 3;
  const int ct = rest & 7, sg = rest >> 3;     // ct 0..7, sg 0..7
  const int row0 = (g8*8 + sg) * 128;          // flat row in [0,8192)
  const int b = row0 >> 11;

  const unsigned short* pB[3];
  unsigned short* dB[3];
#pragma unroll
  for (int t = 0; t < 2; ++t) {
    int I  = wv + t*4;
    int rl = I*8 + (lane >> 3);
    int gk = (lane & 7) ^ (rl & 7);
    pB[t] = Vt + ((size_t)(b*VTR + ct*64 + rl))*NN + gk*8;
    dB[t] = &sB[0][0] + I*512;
  }
  {
    int x  = lane >> 3;                        // den head row
    int gk = (lane & 7) ^ (x & 7);
    pB[2] = Vt + ((size_t)(b*VTR + 512 + x))*NN + gk*8;
    dB[2] = &sB[0][0] + 8*512;                 // local rows 64..71
  }
  // zero sB rows 72..95 once (never overwritten by DMA)
  for (int idx = tid; idx < 384; idx += 256)
    ((uint4*)&sB[72][0])[idx] = uint4{0u,0u,0u,0u};

  const int* adjp = adj + (size_t)b*NN*NN + (size_t)(row0 & 2047)*NN
                    + (tid >> 3)*NN + (tid & 7)*8;
  unsigned short* sAp = &sA[tid >> 3][(tid & 7)*8];

  const int wi = wv >> 1, wc = wv & 1;
  const int l31 = lane & 31, half = lane >> 5;
  f32x16 acc0 = {}; f32x16 acc1 = {}; f32x16 acc2 = {};
  const unsigned short* aRd0 = &sA[wi*64 +      l31][half*8];
  const unsigned short* aRd1 = &sA[wi*64 + 32 + l31][half*8];
  const unsigned short* aRd2 = &sA[wv*32 +      l31][half*8];
  const int nloc = wc*32 + l31;

  for (int k0 = 0; k0 < NN; k0 += 64) {
    load_lds16(pB[0] + k0, dB[0]);
    load_lds16(pB[1] + k0, dB[1]);
    if (wv == 0) load_lds16(pB[2] + k0, dB[2]);
#pragma unroll
    for (int rr = 0; rr < 4; ++rr) {
      const int* p = adjp + rr*32*NN + k0;
      int4 q0 = *(const int4*)p;
      int4 q1 = *(const int4*)(p + 4);
      uint4 u;
      u.x = (unsigned)(q0.x | (q0.y << 16)) * 0x3F80u;
      u.y = (unsigned)(q0.z | (q0.w << 16)) * 0x3F80u;
      u.z = (unsigned)(q1.x | (q1.y << 16)) * 0x3F80u;
      u.w = (unsigned)(q1.z | (q1.w << 16)) * 0x3F80u;
      *(uint4*)(sAp + rr*32*72) = u;
    }
    __syncthreads();
#pragma unroll
    for (int kb = 0; kb < 4; ++kb) {
      int kg = (kb*2 + half) ^ (lane & 7);
      bhalf8 bf  = *(const bhalf8*)&sB[nloc][kg*8];
      bhalf8 bf2 = *(const bhalf8*)&sB[64 + l31][kg*8];   // rows>=72 read zeros
      bhalf8 a0 = *(const bhalf8*)(aRd0 + kb*16);
      bhalf8 a1 = *(const bhalf8*)(aRd1 + kb*16);
      bhalf8 a2 = *(const bhalf8*)(aRd2 + kb*16);
      acc0 = __builtin_amdgcn_mfma_f32_32x32x16_bf16(a0, bf,  acc0, 0, 0, 0);
      acc1 = __builtin_amdgcn_mfma_f32_32x32x16_bf16(a1, bf,  acc1, 0, 0, 0);
      acc2 = __builtin_amdgcn_mfma_f32_32x32x16_bf16(a2, bf2, acc2, 0, 0, 0);
    }
    __syncthreads();
  }
  // den extraction: output col of acc2 == den head index (l31)
  if (l31 == ct) {
#pragma unroll
    for (int reg = 0; reg < 16; ++reg)
      denL[wv*32 + (reg & 3) + 8*(reg >> 2) + 4*half] = acc2[reg];
  }
  __syncthreads();
  // fused div + elu + raw-reshape remap store
  const int ib = row0 & 2047;
#pragma unroll
  for (int mi = 0; mi < 2; ++mi) {
    const f32x16 a = mi ? acc1 : acc0;
#pragma unroll
    for (int reg = 0; reg < 16; ++reg) {
      int il = wi*64 + mi*32 + (reg & 3) + 8*(reg >> 2) + 4*half;
      int i  = ib + il;
      float v = a[reg] / denL[il];
      v = v > 0.f ? v : expm1f(v);
      int n = (ct << 8) | (i >> 3);
      int f = ((i & 7) << 6) | nloc;
      out[((size_t)b*NN + n)*FOUT + f] = v;
    }
  }
}

// ---------------------------------------------------------------------------
extern "C" void kernel_launch(void* const* d_in, const int* in_sizes, int n_in,
                              void* d_out, int out_size, void* d_ws, size_t ws_size,
                              hipStream_t stream)
{
  const float* hin = (const float*)d_in[0];   // h   f32 [4,2048,512]
  const int*   adj = (const int*)d_in[1];     // adj int32 [4,2048,2048]
  // d_in[2] = W_l : mathematically dead (softmax(el[i]+er[j]) == softmax(er[j]))
  const float* Wr  = (const float*)d_in[3];   // W_r f32 [512,512]
  const float* av  = (const float*)d_in[4];   // a   f32 [64,1]
  float* out = (float*)d_out;

  // Workspace overlays (peak 34.9 MB):
  //   [0, 8.39M)      hHi   -> dead after gemm; overlaid by Vt
  //   [8.39M,16.78M)  hLo   -> dead after gemm
  //   [16.78M,17.30M) wTh   -> dead after gemm
  //   [17.30M,17.83M) wTl   -> dead after gemm
  //   [17.83M,34.60M) Whr (f32)
  //   [34.60M,34.86M) er
  //   [0, 8.52M)      Vt (bf16, 520 rows/batch) after gemm
  char* ws = (char*)d_ws;
  unsigned short* hHi = (unsigned short*)(ws);
  unsigned short* hLo = (unsigned short*)(ws + 8388608);
  unsigned short* wTh = (unsigned short*)(ws + 16777216);
  unsigned short* wTl = (unsigned short*)(ws + 17301504);
  float* Whr  = (float*)(ws + 17825792);
  float* er   = (float*)(ws + 34603008);
  unsigned short* Vt = (unsigned short*)(ws);

  k_split_prep   <<<dim3(2112),    256, 0, stream>>>(hin, hHi, hLo, Wr, wTh, wTl);
  k_gemm_whr_mfma<<<dim3(512),     256, 0, stream>>>(hHi, hLo, wTh, wTl, Whr, av, er);
  k_softvt       <<<dim3(8, 8, 4), 256, 0, stream>>>(Whr, er, Vt);
  k_attn_out     <<<dim3(512),     256, 0, stream>>>(adj, Vt, out);
}

// Round 7
// 198.585 us; speedup vs baseline: 1.1973x; 1.0012x over previous
//
#include <hip/hip_runtime.h>

// Problem constants (B,N,F_in,F_out fixed by setup_inputs)
#define NB   4
#define NN   2048
#define FIN  512
#define FOUT 512
#define NHD  8
#define DH   64
#define VTR  520   // Vt rows per batch: 512 data (8 heads x 64 d) + 8 denominator
#define SLOPE 0.2f

typedef __attribute__((ext_vector_type(8)))  short bhalf8;
typedef __attribute__((ext_vector_type(16))) float f32x16;

__device__ __forceinline__ void load_lds16(const void* g, void* l) {
  __builtin_amdgcn_global_load_lds(
      (const __attribute__((address_space(1))) unsigned int*)g,
      (__attribute__((address_space(3))) unsigned int*)l, 16, 0, 0);
}

// RNE float->bf16 (finite values only in this pipeline)
__device__ __forceinline__ unsigned short bfrne(float x) {
  unsigned int u = __float_as_uint(x);
  return (unsigned short)((u + 0x7FFFu + ((u >> 16) & 1u)) >> 16);
}

// split x,y into bf16 hi (RNE) + bf16 lo (RNE of residual); returns packed pairs
__device__ __forceinline__ void split2(float x, float y,
                                       unsigned int& hp, unsigned int& lp) {
  unsigned int ux = __float_as_uint(x), uy = __float_as_uint(y);
  unsigned int rx = (ux + 0x7FFFu + ((ux >> 16) & 1u)) & 0xFFFF0000u;
  unsigned int ry = (uy + 0x7FFFu + ((uy >> 16) & 1u)) & 0xFFFF0000u;
  float lx = x - __uint_as_float(rx);
  float ly = y - __uint_as_float(ry);
  unsigned int vx = __float_as_uint(lx), vy = __float_as_uint(ly);
  hp = (rx >> 16) | ry;
  lp = ((vx + 0x7FFFu + ((vx >> 16) & 1u)) >> 16)
     | ((vy + 0x7FFFu + ((vy >> 16) & 1u)) & 0xFFFF0000u);
}

// ---------------------------------------------------------------------------
// P: blocks [0,2048): h -> hHi/hLo split; [2048,2112): Wr transpose+split.
// ---------------------------------------------------------------------------
__global__ __launch_bounds__(256) void k_split_prep(
    const float* __restrict__ h,
    unsigned short* __restrict__ hHi, unsigned short* __restrict__ hLo,
    const float* __restrict__ Wr,
    unsigned short* __restrict__ wTh, unsigned short* __restrict__ wTl)
{
  __shared__ float s[64][65];
  const int t = threadIdx.x;
  if (blockIdx.x < 2048) {
    size_t base = ((size_t)blockIdx.x * 256 + t) * 8;
    float4 a = *(const float4*)(h + base);
    float4 b = *(const float4*)(h + base + 4);
    uint4 uh, ul;
    split2(a.x, a.y, uh.x, ul.x);
    split2(a.z, a.w, uh.y, ul.y);
    split2(b.x, b.y, uh.z, ul.z);
    split2(b.z, b.w, uh.w, ul.w);
    *(uint4*)(hHi + base) = uh;
    *(uint4*)(hLo + base) = ul;
    return;
  }
  const int bid2 = blockIdx.x - 2048;
  const int n0 = (bid2 & 7) * 64, k0 = (bid2 >> 3) * 64;
#pragma unroll
  for (int p = 0; p < 4; ++p) {
    int row = p * 16 + (t >> 4);       // k-local
    int col = (t & 15) * 4;            // n-local
    float4 v = *(const float4*)(Wr + (size_t)(k0 + row) * FOUT + n0 + col);
    s[row][col] = v.x; s[row][col+1] = v.y; s[row][col+2] = v.z; s[row][col+3] = v.w;
  }
  __syncthreads();
  const int n = t >> 2;           // 0..63
  const int ks = (t & 3) * 16;    // 0,16,32,48
  uint4 h0, h1, l0, l1;
  split2(s[ks+ 0][n], s[ks+ 1][n], h0.x, l0.x);
  split2(s[ks+ 2][n], s[ks+ 3][n], h0.y, l0.y);
  split2(s[ks+ 4][n], s[ks+ 5][n], h0.z, l0.z);
  split2(s[ks+ 6][n], s[ks+ 7][n], h0.w, l0.w);
  split2(s[ks+ 8][n], s[ks+ 9][n], h1.x, l1.x);
  split2(s[ks+10][n], s[ks+11][n], h1.y, l1.y);
  split2(s[ks+12][n], s[ks+13][n], h1.z, l1.z);
  split2(s[ks+14][n], s[ks+15][n], h1.w, l1.w);
  size_t o = (size_t)(n0 + n) * FIN + k0 + ks;
  *(uint4*)(wTh + o) = h0; *(uint4*)(wTh + o + 8) = h1;
  *(uint4*)(wTl + o) = l0; *(uint4*)(wTl + o + 8) = l1;
}

// ---------------------------------------------------------------------------
// K1: Whr = leaky_relu(h @ Wr) split-bf16 MFMA. Epilogue computes er[row]
//     (dot with a) via 32-lane shuffle + LDS combine of the 2 col-waves ->
//     plain store. Each (row,ct) block covers all 64 d's of er-row.
// ---------------------------------------------------------------------------
__global__ __launch_bounds__(256) void k_gemm_whr_mfma(
    const unsigned short* __restrict__ hHi, const unsigned short* __restrict__ hLo,
    const unsigned short* __restrict__ wTh, const unsigned short* __restrict__ wTl,
    float* __restrict__ Whr, const float* __restrict__ av, float* __restrict__ er)
{
  __shared__ unsigned short sAh[128*64], sAl[128*64];
  __shared__ unsigned short sBh[64*64],  sBl[64*64];
  __shared__ float erT[128][2];
  const int tid = threadIdx.x, lane = tid & 63, wv = tid >> 6;
  const int Bid = blockIdx.x;
  const int g8 = Bid & 7, idx = Bid >> 3;     // XCD-grouped
  const int sg = idx >> 3, ct = idx & 7;      // col tiles sweep fastest
  const int c0 = ct * 64;
  const int row0 = (g8 * 8 + sg) * 128;

  const unsigned short* pAh[4]; const unsigned short* pAl[4];
  unsigned short *dAh[4], *dAl[4];
#pragma unroll
  for (int t = 0; t < 4; ++t) {
    int I  = wv + t * 4;
    int rl = I * 8 + (lane >> 3);
    int gk = (lane & 7) ^ (rl & 7);
    pAh[t] = hHi + (size_t)(row0 + rl) * FIN + gk * 8;
    pAl[t] = hLo + (size_t)(row0 + rl) * FIN + gk * 8;
    dAh[t] = sAh + I * 512;  dAl[t] = sAl + I * 512;
  }
  const unsigned short* pBh[2]; const unsigned short* pBl[2];
  unsigned short *dBh[2], *dBl[2];
#pragma unroll
  for (int t = 0; t < 2; ++t) {
    int I  = wv + t * 4;
    int rl = I * 8 + (lane >> 3);
    int gk = (lane & 7) ^ (rl & 7);
    pBh[t] = wTh + (size_t)(c0 + rl) * FIN + gk * 8;
    pBl[t] = wTl + (size_t)(c0 + rl) * FIN + gk * 8;
    dBh[t] = sBh + I * 512;  dBl[t] = sBl + I * 512;
  }

  const int wi = wv >> 1, wc = wv & 1;
  const int l31 = lane & 31, half = lane >> 5;
  const int aoff0 = (wi*64 +      l31) * 64;
  const int aoff1 = (wi*64 + 32 + l31) * 64;
  const int boff  = (wc*32 +      l31) * 64;
  f32x16 acc0 = {}; f32x16 acc1 = {};

  for (int k0 = 0; k0 < FIN; k0 += 64) {
#pragma unroll
    for (int t = 0; t < 4; ++t) { load_lds16(pAh[t] + k0, dAh[t]);
                                  load_lds16(pAl[t] + k0, dAl[t]); }
#pragma unroll
    for (int t = 0; t < 2; ++t) { load_lds16(pBh[t] + k0, dBh[t]);
                                  load_lds16(pBl[t] + k0, dBl[t]); }
    __syncthreads();
#pragma unroll
    for (int kb = 0; kb < 4; ++kb) {
      int kg = ((kb*2 + half) ^ (lane & 7)) * 8;
      bhalf8 bh  = *(const bhalf8*)&sBh[boff  + kg];
      bhalf8 bl  = *(const bhalf8*)&sBl[boff  + kg];
      bhalf8 a0h = *(const bhalf8*)&sAh[aoff0 + kg];
      bhalf8 a0l = *(const bhalf8*)&sAl[aoff0 + kg];
      bhalf8 a1h = *(const bhalf8*)&sAh[aoff1 + kg];
      bhalf8 a1l = *(const bhalf8*)&sAl[aoff1 + kg];
      acc0 = __builtin_amdgcn_mfma_f32_32x32x16_bf16(a0h, bh, acc0, 0, 0, 0);
      acc1 = __builtin_amdgcn_mfma_f32_32x32x16_bf16(a1h, bh, acc1, 0, 0, 0);
      acc0 = __builtin_amdgcn_mfma_f32_32x32x16_bf16(a0l, bh, acc0, 0, 0, 0);
      acc1 = __builtin_amdgcn_mfma_f32_32x32x16_bf16(a1l, bh, acc1, 0, 0, 0);
      acc0 = __builtin_amdgcn_mfma_f32_32x32x16_bf16(a0h, bl, acc0, 0, 0, 0);
      acc1 = __builtin_amdgcn_mfma_f32_32x32x16_bf16(a1h, bl, acc1, 0, 0, 0);
    }
    __syncthreads();
  }

  // epilogue: leaky_relu + remap store + er partial (dd = wc*32+l31)
  const float a_d = av[wc*32 + l31];
#pragma unroll
  for (int mi = 0; mi < 2; ++mi) {
    const f32x16 a = mi ? acc1 : acc0;
#pragma unroll
    for (int reg = 0; reg < 16; ++reg) {
      int rmap = (reg & 3) + 8*(reg >> 2) + 4*half;
      int rowloc = wi*64 + mi*32 + rmap;
      int grow = row0 + rowloc;
      int b  = grow >> 11;
      int n  = grow & 2047;
      int hd = n >> 8;
      int jj = ((n & 255) << 3) | ct;
      float v = a[reg];
      v = v > 0.f ? v : SLOPE * v;
      Whr[(((size_t)(b*NHD + hd)) * NN + jj) * DH + (wc*32 + l31)] = v;
      float p = v * a_d;
      p += __shfl_xor(p, 16, 32);
      p += __shfl_xor(p,  8, 32);
      p += __shfl_xor(p,  4, 32);
      p += __shfl_xor(p,  2, 32);
      p += __shfl_xor(p,  1, 32);
      if (l31 == 0) erT[rowloc][wc] = p;
    }
  }
  __syncthreads();
  if (tid < 128) {
    int grow = row0 + tid;
    int b  = grow >> 11;
    int n  = grow & 2047;
    int hd = n >> 8;
    int jj = ((n & 255) << 3) | ct;
    er[((size_t)(b*NHD + hd)) * NN + jj] = erT[tid][0] + erT[tid][1];
  }
}

// ---------------------------------------------------------------------------
// K2: fused softmax + Vt build. Grid (jc=8, h=8, b=4).
// ---------------------------------------------------------------------------
__global__ __launch_bounds__(256) void k_softvt(
    const float* __restrict__ Whr, const float* __restrict__ er,
    unsigned short* __restrict__ Vt)
{
  __shared__ float wm[4];
  __shared__ float wbuf[256];
  __shared__ unsigned short tile[64][264];   // [d][j-local], padded
  const int tid = threadIdx.x;
  const int jc = blockIdx.x, hh = blockIdx.y, b = blockIdx.z;
  const float* ep = er + ((size_t)(b*NHD + hh)) * NN;
  float m = -1e30f;
  for (int j = tid; j < NN; j += 256) m = fmaxf(m, ep[j]);
#pragma unroll
  for (int off = 32; off; off >>= 1) m = fmaxf(m, __shfl_down(m, off, 64));
  if ((tid & 63) == 0) wm[tid >> 6] = m;
  __syncthreads();
  const float mm = fmaxf(fmaxf(wm[0], wm[1]), fmaxf(wm[2], wm[3]));
  const int j0 = jc * 256;
  float w = expf(ep[j0 + tid] - mm);
  wbuf[tid] = w;
  Vt[((size_t)(b*VTR + 512 + hh)) * NN + j0 + tid] = bfrne(w);
  __syncthreads();
  const size_t wbase = ((size_t)(b*NHD + hh)) * NN;
#pragma unroll
  for (int p = 0; p < 16; ++p) {
    int jr = p*16 + (tid >> 4);
    int dc = (tid & 15) * 4;
    float4 v = *(const float4*)(Whr + (wbase + j0 + jr) * DH + dc);
    float wj = wbuf[jr];
    tile[dc+0][jr] = bfrne(v.x * wj);
    tile[dc+1][jr] = bfrne(v.y * wj);
    tile[dc+2][jr] = bfrne(v.z * wj);
    tile[dc+3][jr] = bfrne(v.w * wj);
  }
  __syncthreads();
#pragma unroll
  for (int q = 0; q < 8; ++q) {
    int idx = q*256 + tid;
    int d = idx >> 5, seg = idx & 31;
    uint4 t16 = *(const uint4*)&tile[d][seg*8];
    *(uint4*)(Vt + ((size_t)(b*VTR + hh*64 + d)) * NN + j0 + seg*8) = t16;
  }
}

// ---------------------------------------------------------------------------
// K3: fused attention matmul + epilogue, software-pipelined.
//   - sB double-buffered (2 x 72 rows x 64 k): DMA(k+1) issued at top of
//     compute(k) -> latency hidden behind MFMA instead of barrier-serialized.
//   - adj prefetched into regs one iteration ahead (8 x int4).
//   - den MFMA reuses the wave's own a0/a1 frag (rows wv*32..+31); its B-frag
//     is predicated: lanes l31<8 read den rows (conflict-free), others zero.
//   - epilogue: v = num/den, elu, raw-reshape remap, direct store to out.
// ---------------------------------------------------------------------------
__global__ __launch_bounds__(256) void k_attn_out(
    const int* __restrict__ adj, const unsigned short* __restrict__ Vt,
    float* __restrict__ out)
{
  __shared__ unsigned short sA[128][72];     // [i][k], +8 pad (16B-aligned rows)
  __shared__ unsigned short sB[2][72*64];    // dbuf: rows 0..63 data, 64..71 den
  __shared__ float denL[128];
  const int tid = threadIdx.x;
  const int lane = tid & 63, wv = tid >> 6;
  const int Bid = blockIdx.x;
  const int g8 = Bid & 7, rest = Bid >> 3;
  const int ct = rest & 7, sg = rest >> 3;     // ct 0..7, sg 0..7
  const int row0 = (g8*8 + sg) * 128;          // flat row in [0,8192)
  const int b = row0 >> 11;

  const unsigned short* pB[3];
  int dOff[3];
#pragma unroll
  for (int t = 0; t < 2; ++t) {
    int I  = wv + t*4;
    int rl = I*8 + (lane >> 3);
    int gk = (lane & 7) ^ (rl & 7);
    pB[t] = Vt + ((size_t)(b*VTR + ct*64 + rl))*NN + gk*8;
    dOff[t] = I*512;
  }
  {
    int x  = lane >> 3;                        // den head row
    int gk = (lane & 7) ^ (x & 7);
    pB[2] = Vt + ((size_t)(b*VTR + 512 + x))*NN + gk*8;
    dOff[2] = 64*64;                           // local rows 64..71
  }

  const int* adjp = adj + (size_t)b*NN*NN + (size_t)(row0 & 2047)*NN
                    + (tid >> 3)*NN + (tid & 7)*8;
  unsigned short* sAp = &sA[tid >> 3][(tid & 7)*8];

  const int wi = wv >> 1, wc = wv & 1;
  const int l31 = lane & 31, half = lane >> 5;
  f32x16 acc0 = {}; f32x16 acc1 = {}; f32x16 acc2 = {};
  const unsigned short* aRd0 = &sA[wi*64 +      l31][half*8];
  const unsigned short* aRd1 = &sA[wi*64 + 32 + l31][half*8];
  const int nloc = wc*32 + l31;

  // prologue: DMA B(0) into buf0, adj(0) into regs
  load_lds16(pB[0], &sB[0][dOff[0]]);
  load_lds16(pB[1], &sB[0][dOff[1]]);
  if (wv == 0) load_lds16(pB[2], &sB[0][dOff[2]]);
  int4 q[8];
#pragma unroll
  for (int rr = 0; rr < 4; ++rr) {
    q[2*rr]   = *(const int4*)(adjp + rr*32*NN);
    q[2*rr+1] = *(const int4*)(adjp + rr*32*NN + 4);
  }

  for (int it = 0; it < 32; ++it) {
    const int cur = it & 1;
    // stage A(it) from prefetched regs
#pragma unroll
    for (int rr = 0; rr < 4; ++rr) {
      uint4 u;
      u.x = (unsigned)(q[2*rr].x   | (q[2*rr].y   << 16)) * 0x3F80u;
      u.y = (unsigned)(q[2*rr].z   | (q[2*rr].w   << 16)) * 0x3F80u;
      u.z = (unsigned)(q[2*rr+1].x | (q[2*rr+1].y << 16)) * 0x3F80u;
      u.w = (unsigned)(q[2*rr+1].z | (q[2*rr+1].w << 16)) * 0x3F80u;
      *(uint4*)(sAp + rr*32*72) = u;
    }
    __syncthreads();
    // issue next iteration's staging early (hidden behind compute)
    if (it < 31) {
      const int nk = (it + 1) * 64;
      unsigned short* nb = sB[cur ^ 1];
      load_lds16(pB[0] + nk, nb + dOff[0]);
      load_lds16(pB[1] + nk, nb + dOff[1]);
      if (wv == 0) load_lds16(pB[2] + nk, nb + dOff[2]);
#pragma unroll
      for (int rr = 0; rr < 4; ++rr) {
        q[2*rr]   = *(const int4*)(adjp + rr*32*NN + nk);
        q[2*rr+1] = *(const int4*)(adjp + rr*32*NN + nk + 4);
      }
    }
    const unsigned short* sBc = sB[cur];
#pragma unroll
    for (int kb = 0; kb < 4; ++kb) {
      int kg = (kb*2 + half) ^ (lane & 7);
      bhalf8 bf  = *(const bhalf8*)&sBc[nloc*64 + kg*8];
      bhalf8 bf2 = {};
      if (l31 < 8) bf2 = *(const bhalf8*)&sBc[(64 + l31)*64 + kg*8];
      bhalf8 a0 = *(const bhalf8*)(aRd0 + kb*16);
      bhalf8 a1 = *(const bhalf8*)(aRd1 + kb*16);
      acc0 = __builtin_amdgcn_mfma_f32_32x32x16_bf16(a0, bf,  acc0, 0, 0, 0);
      acc1 = __builtin_amdgcn_mfma_f32_32x32x16_bf16(a1, bf,  acc1, 0, 0, 0);
      acc2 = __builtin_amdgcn_mfma_f32_32x32x16_bf16(wc ? a1 : a0, bf2, acc2, 0, 0, 0);
    }
    __syncthreads();
  }
  // den extraction: acc2 rows = wv*32 + rowmap, output col (l31) == den head
  if (l31 == ct) {
#pragma unroll
    for (int reg = 0; reg < 16; ++reg)
      denL[wv*32 + (reg & 3) + 8*(reg >> 2) + 4*half] = acc2[reg];
  }
  __syncthreads();
  // fused div + elu + raw-reshape remap store
  const int ib = row0 & 2047;
#pragma unroll
  for (int mi = 0; mi < 2; ++mi) {
    const f32x16 a = mi ? acc1 : acc0;
#pragma unroll
    for (int reg = 0; reg < 16; ++reg) {
      int il = wi*64 + mi*32 + (reg & 3) + 8*(reg >> 2) + 4*half;
      int i  = ib + il;
      float v = a[reg] / denL[il];
      v = v > 0.f ? v : expm1f(v);
      int n = (ct << 8) | (i >> 3);
      int f = ((i & 7) << 6) | nloc;
      out[((size_t)b*NN + n)*FOUT + f] = v;
    }
  }
}

// ---------------------------------------------------------------------------
extern "C" void kernel_launch(void* const* d_in, const int* in_sizes, int n_in,
                              void* d_out, int out_size, void* d_ws, size_t ws_size,
                              hipStream_t stream)
{
  const float* hin = (const float*)d_in[0];   // h   f32 [4,2048,512]
  const int*   adj = (const int*)d_in[1];     // adj int32 [4,2048,2048]
  // d_in[2] = W_l : mathematically dead (softmax(el[i]+er[j]) == softmax(er[j]))
  const float* Wr  = (const float*)d_in[3];   // W_r f32 [512,512]
  const float* av  = (const float*)d_in[4];   // a   f32 [64,1]
  float* out = (float*)d_out;

  // Workspace overlays (peak 34.9 MB):
  //   [0, 8.39M)      hHi   -> dead after gemm; overlaid by Vt
  //   [8.39M,16.78M)  hLo   -> dead after gemm
  //   [16.78M,17.30M) wTh   -> dead after gemm
  //   [17.30M,17.83M) wTl   -> dead after gemm
  //   [17.83M,34.60M) Whr (f32)
  //   [34.60M,34.86M) er
  //   [0, 8.52M)      Vt (bf16, 520 rows/batch) after gemm
  char* ws = (char*)d_ws;
  unsigned short* hHi = (unsigned short*)(ws);
  unsigned short* hLo = (unsigned short*)(ws + 8388608);
  unsigned short* wTh = (unsigned short*)(ws + 16777216);
  unsigned short* wTl = (unsigned short*)(ws + 17301504);
  float* Whr  = (float*)(ws + 17825792);
  float* er   = (float*)(ws + 34603008);
  unsigned short* Vt = (unsigned short*)(ws);

  k_split_prep   <<<dim3(2112),    256, 0, stream>>>(hin, hHi, hLo, Wr, wTh, wTl);
  k_gemm_whr_mfma<<<dim3(512),     256, 0, stream>>>(hHi, hLo, wTh, wTl, Whr, av, er);
  k_softvt       <<<dim3(8, 8, 4), 256, 0, stream>>>(Whr, er, Vt);
  k_attn_out     <<<dim3(512),     256, 0, stream>>>(adj, Vt, out);
}